// Round 9
// baseline (210.930 us; speedup 1.0000x reference)
//
#include <hip/hip_runtime.h>
#include <math.h>

#define NF 128
#define HD 8
#define NPG 2000          // nodes per graph
#define EPB 8000          // edges per sort chunk (4 chunks per graph)
#define TBL4 (NPG * HD / 4)   // 4000 float4 per graph slice
#define SLOPE 0.01f

__device__ __forceinline__ float lrelu(float v) {
    return v > 0.0f ? v : SLOPE * v;
}

// ---------------------------------------------------------------------------
// K1: t1 = x @ W1a  (N x 128)@(128 x 8), coalesced via LDS staging.
// ---------------------------------------------------------------------------
__global__ __launch_bounds__(256) void k_feat(const float* __restrict__ x,
                                              const float* __restrict__ W1a,
                                              float* __restrict__ t1, int N) {
    __shared__ float tile[64 * 132];   // 33 KiB
    __shared__ float wl[NF * HD];      // 4 KiB

    const int t = threadIdx.x;
    const size_t base = (size_t)blockIdx.x * 64;

    ((float4*)wl)[t] = ((const float4*)W1a)[t];

    const float4* xg = (const float4*)(x + base * NF);
#pragma unroll
    for (int i = 0; i < 8; ++i) {
        int f4 = t + i * 256;
        float4 v = xg[f4];
        int flat = f4 * 4;
        int n = flat >> 7;
        int k = flat & 127;
        *(float4*)(tile + n * 132 + k) = v;
    }
    __syncthreads();

    const int n = t >> 2;
    const int c0 = (t & 3) * 2;
    float acc0 = 0.0f, acc1 = 0.0f;
    const float* row = tile + n * 132;
#pragma unroll
    for (int k4 = 0; k4 < 32; ++k4) {
        float4 r = *(const float4*)(row + k4 * 4);
        int kb = k4 * 4 * HD;
        acc0 += r.x * wl[kb + c0];          acc1 += r.x * wl[kb + c0 + 1];
        acc0 += r.y * wl[kb + HD + c0];     acc1 += r.y * wl[kb + HD + c0 + 1];
        acc0 += r.z * wl[kb + 2*HD + c0];   acc1 += r.z * wl[kb + 2*HD + c0 + 1];
        acc0 += r.w * wl[kb + 3*HD + c0];   acc1 += r.w * wl[kb + 3*HD + c0 + 1];
    }
    *(float2*)(t1 + (base + n) * HD + c0) = make_float2(acc0, acc1);
}

// ---------------------------------------------------------------------------
// K2: per-chunk counting sort, fully in LDS. 256 blocks (4 per graph).
// Count (ds_add_u32) -> block shfl scan -> LDS scatter (ds_add_rtn) ->
// coalesced dump of sorted LOCAL srcs + row_ptr.
// ---------------------------------------------------------------------------
__global__ __launch_bounds__(1024) void k_sort(const int* __restrict__ ei,
                                               int* __restrict__ gcol,
                                               int* __restrict__ rpc,
                                               int E) {
    __shared__ int cnt[NPG];      // counts -> cursors (8 KB)
    __shared__ int srt[EPB];      // sorted srcs (32 KB)
    __shared__ int wtot[16], wpre[16];

    const int b = blockIdx.x;     // chunk id
    const int g = b >> 2;
    const int tid = threadIdx.x;
    const int lane = tid & 63;
    const int wv = tid >> 6;
    const int nodeBase = g * NPG;
    const int e0 = b * EPB;

    for (int i = tid; i < NPG; i += 1024) cnt[i] = 0;
    __syncthreads();

    // count pass
    for (int e = e0 + tid; e < e0 + EPB; e += 1024) {
        int dl = ei[E + e] - nodeBase;
        atomicAdd(&cnt[dl], 1);               // native ds_add_u32
    }
    __syncthreads();

    // block-wide exclusive scan; thread t owns pair (2t, 2t+1)
    int c0 = 0, c1 = 0;
    if (tid < 1000) { c0 = cnt[2 * tid]; c1 = cnt[2 * tid + 1]; }
    int s = c0 + c1;
    int isc = s;
#pragma unroll
    for (int d = 1; d < 64; d <<= 1) {
        int o = __shfl_up(isc, d);
        if (lane >= d) isc += o;
    }
    if (lane == 63) wtot[wv] = isc;
    __syncthreads();
    if (wv == 0) {
        int v = (lane < 16) ? wtot[lane] : 0;
        int iv = v;
#pragma unroll
        for (int d = 1; d < 16; d <<= 1) {
            int o = __shfl_up(iv, d);
            if (lane >= d) iv += o;
        }
        if (lane < 16) wpre[lane] = iv - v;
    }
    __syncthreads();
    int excl = isc - s + wpre[wv];

    int* rpb = rpc + (size_t)b * (NPG + 1);
    if (tid < 1000) {
        cnt[2 * tid]     = excl;
        cnt[2 * tid + 1] = excl + c0;
        rpb[2 * tid]     = excl;
        rpb[2 * tid + 1] = excl + c0;
    }
    if (tid == 0) rpb[NPG] = EPB;
    __syncthreads();

    // scatter pass into LDS (store LOCAL src index)
    for (int e = e0 + tid; e < e0 + EPB; e += 1024) {
        int src = ei[e] - nodeBase;
        int dl = ei[E + e] - nodeBase;
        int pos = atomicAdd(&cnt[dl], 1);     // ds_add_rtn_u32 (native int)
        srt[pos] = src;
    }
    __syncthreads();

    // coalesced dump
    int4* dst4 = (int4*)(gcol + (size_t)b * EPB);
    const int4* s4 = (const int4*)srt;
    for (int i = tid; i < EPB / 4; i += 1024) dst4[i] = s4[i];
}

// ---------------------------------------------------------------------------
// K3: layer 1, one block per graph. Stage the graph's full t1 slice (64 KB)
// into LDS (BOUNDS-GUARDED: 4000 float4, not 4096 — R8's overflow clobbered
// wts[]), then gather via ds_read, MLP1, u = h@W2a -> global (coalesced).
// ---------------------------------------------------------------------------
__global__ __launch_bounds__(1024) void k_l1(
    const float* __restrict__ t1, const int* __restrict__ rpc,
    const int* __restrict__ gcol, float* __restrict__ u,
    const float* __restrict__ b1a, const float* __restrict__ W1b,
    const float* __restrict__ b1b, const float* __restrict__ W2a)
{
    __shared__ float tbl[NPG * HD];   // 62.5 KiB
    __shared__ float wts[144];        // b1a[8] W1b[64] b1b[8] W2a[64]

    const int g = blockIdx.x;
    const int tid = threadIdx.x;

    if (tid < 144) {
        float v;
        if (tid < 8)       v = b1a[tid];
        else if (tid < 72) v = W1b[tid - 8];
        else if (tid < 80) v = b1b[tid - 72];
        else               v = W2a[tid - 80];
        wts[tid] = v;
    }

    // stage t1 slice (4000 float4), coalesced, bounds-guarded
    const float4* src4 = (const float4*)(t1 + (size_t)g * NPG * HD);
    float4* tbl4 = (float4*)tbl;
#pragma unroll
    for (int i = 0; i < 3; ++i) tbl4[tid + i * 1024] = src4[tid + i * 1024];
    if (tid + 3 * 1024 < TBL4) tbl4[tid + 3 * 1024] = src4[tid + 3 * 1024];
    __syncthreads();

    for (int nl = tid; nl < NPG; nl += 1024) {
        float a0 = 0, a1 = 0, a2 = 0, a3 = 0, a4 = 0, a5 = 0, a6 = 0, a7 = 0;
#pragma unroll
        for (int p = 0; p < 4; ++p) {
            const int* rpb  = rpc + (size_t)((g << 2) + p) * (NPG + 1);
            const int* colp = gcol + (size_t)((g << 2) + p) * EPB;
            int rs = rpb[nl], re = rpb[nl + 1];
            for (int e = rs; e < re; ++e) {
                int sl = colp[e];                       // local src
                const float* row = tbl + sl * HD;       // LDS gather
                float4 pa = *(const float4*)row;
                float4 pb = *(const float4*)(row + 4);
                a0 += pa.x; a1 += pa.y; a2 += pa.z; a3 += pa.w;
                a4 += pb.x; a5 += pb.y; a6 += pb.z; a7 += pb.w;
            }
        }
        const float* ti = tbl + nl * HD;                // self feature (LDS)
        float z[HD];
        z[0] = lrelu(ti[0] + a0 + wts[0]); z[1] = lrelu(ti[1] + a1 + wts[1]);
        z[2] = lrelu(ti[2] + a2 + wts[2]); z[3] = lrelu(ti[3] + a3 + wts[3]);
        z[4] = lrelu(ti[4] + a4 + wts[4]); z[5] = lrelu(ti[5] + a5 + wts[5]);
        z[6] = lrelu(ti[6] + a6 + wts[6]); z[7] = lrelu(ti[7] + a7 + wts[7]);

        float h[HD];
#pragma unroll
        for (int j = 0; j < HD; ++j) {
            float acc = wts[72 + j];
#pragma unroll
            for (int c = 0; c < HD; ++c) acc += z[c] * wts[8 + c * HD + j];
            h[j] = lrelu(acc);
        }
        float uu[HD];
#pragma unroll
        for (int j = 0; j < HD; ++j) {
            float acc = 0.0f;
#pragma unroll
            for (int c = 0; c < HD; ++c) acc += h[c] * wts[80 + c * HD + j];
            uu[j] = acc;
        }
        float* ur = u + ((size_t)g * NPG + nl) * HD;
        *(float4*)ur       = make_float4(uu[0], uu[1], uu[2], uu[3]);
        *(float4*)(ur + 4) = make_float4(uu[4], uu[5], uu[6], uu[7]);
    }
}

// ---------------------------------------------------------------------------
// K4: layer 2 + readout, one block per graph. Stage u slice into LDS
// (bounds-guarded), gather from LDS, MLP2 + FC1 + FC2, block reduce,
// log_softmax -> out.
// ---------------------------------------------------------------------------
__global__ __launch_bounds__(1024) void k_l2fin(
    const float* __restrict__ u, const int* __restrict__ rpc,
    const int* __restrict__ gcol,
    const float* __restrict__ b2a, const float* __restrict__ W2b,
    const float* __restrict__ b2b, const float* __restrict__ Wf1,
    const float* __restrict__ bf1, const float* __restrict__ Wf2,
    const float* __restrict__ bf2, float* __restrict__ out)
{
    __shared__ float tbl[NPG * HD];   // 62.5 KiB
    __shared__ float wts[89];         // b2a[8] W2b[64] b2b[8] Wf1[8] bf1[1]
    __shared__ float red[32];

    const int g = blockIdx.x;
    const int tid = threadIdx.x;
    const int lane = tid & 63;
    const int wv = tid >> 6;

    if (tid < 89) {
        float v;
        if (tid < 8)       v = b2a[tid];
        else if (tid < 72) v = W2b[tid - 8];
        else if (tid < 80) v = b2b[tid - 72];
        else if (tid < 88) v = Wf1[tid - 80];
        else               v = bf1[0];
        wts[tid] = v;
    }

    // stage u slice, coalesced, bounds-guarded
    const float4* src4 = (const float4*)(u + (size_t)g * NPG * HD);
    float4* tbl4 = (float4*)tbl;
#pragma unroll
    for (int i = 0; i < 3; ++i) tbl4[tid + i * 1024] = src4[tid + i * 1024];
    if (tid + 3 * 1024 < TBL4) tbl4[tid + 3 * 1024] = src4[tid + 3 * 1024];
    __syncthreads();

    float acc0 = 0.0f, acc1 = 0.0f;
    for (int nl = tid; nl < NPG; nl += 1024) {
        float a0 = 0, a1 = 0, a2 = 0, a3 = 0, a4 = 0, a5 = 0, a6 = 0, a7 = 0;
#pragma unroll
        for (int p = 0; p < 4; ++p) {
            const int* rpb  = rpc + (size_t)((g << 2) + p) * (NPG + 1);
            const int* colp = gcol + (size_t)((g << 2) + p) * EPB;
            int rs = rpb[nl], re = rpb[nl + 1];
            for (int e = rs; e < re; ++e) {
                int sl = colp[e];
                const float* row = tbl + sl * HD;
                float4 pa = *(const float4*)row;
                float4 pb = *(const float4*)(row + 4);
                a0 += pa.x; a1 += pa.y; a2 += pa.z; a3 += pa.w;
                a4 += pb.x; a5 += pb.y; a6 += pb.z; a7 += pb.w;
            }
        }
        const float* ui = tbl + nl * HD;
        float z[HD];
        z[0] = lrelu(ui[0] + a0 + wts[0]); z[1] = lrelu(ui[1] + a1 + wts[1]);
        z[2] = lrelu(ui[2] + a2 + wts[2]); z[3] = lrelu(ui[3] + a3 + wts[3]);
        z[4] = lrelu(ui[4] + a4 + wts[4]); z[5] = lrelu(ui[5] + a5 + wts[5]);
        z[6] = lrelu(ui[6] + a6 + wts[6]); z[7] = lrelu(ui[7] + a7 + wts[7]);

        float sv = wts[88];
#pragma unroll
        for (int j = 0; j < HD; ++j) {
            float acc = wts[72 + j];
#pragma unroll
            for (int c = 0; c < HD; ++c) acc += z[c] * wts[8 + c * HD + j];
            sv += lrelu(acc) * wts[80 + j];
        }
        float pf = lrelu(sv);
        float2 wf = *(const float2*)(Wf2 + (size_t)nl * 2);
        acc0 += pf * wf.x;
        acc1 += pf * wf.y;
    }

#pragma unroll
    for (int off = 32; off > 0; off >>= 1) {
        acc0 += __shfl_down(acc0, off);
        acc1 += __shfl_down(acc1, off);
    }
    if (lane == 0) { red[wv * 2] = acc0; red[wv * 2 + 1] = acc1; }
    __syncthreads();

    if (tid == 0) {
        float y0 = bf2[0], y1 = bf2[1];
#pragma unroll
        for (int w = 0; w < 16; ++w) { y0 += red[w * 2]; y1 += red[w * 2 + 1]; }
        float m = fmaxf(y0, y1);
        float lse = m + logf(expf(y0 - m) + expf(y1 - m));
        out[g * 2 + 0] = y0 - lse;
        out[g * 2 + 1] = y1 - lse;
    }
}

// ---------------------------------------------------------------------------
extern "C" void kernel_launch(void* const* d_in, const int* in_sizes, int n_in,
                              void* d_out, int out_size, void* d_ws, size_t ws_size,
                              hipStream_t stream) {
    const float* x   = (const float*)d_in[0];
    const int*   ei  = (const int*)  d_in[1];
    const float* W1a = (const float*)d_in[3];
    const float* b1a = (const float*)d_in[4];
    const float* W1b = (const float*)d_in[5];
    const float* b1b = (const float*)d_in[6];
    const float* W2a = (const float*)d_in[7];
    const float* b2a = (const float*)d_in[8];
    const float* W2b = (const float*)d_in[9];
    const float* b2b = (const float*)d_in[10];
    const float* Wf1 = (const float*)d_in[11];
    const float* bf1 = (const float*)d_in[12];
    const float* Wf2 = (const float*)d_in[13];
    const float* bf2 = (const float*)d_in[14];

    int N   = in_sizes[0] / NF;        // 128000
    int E   = in_sizes[1] / 2;         // 2048000
    int Bn  = N / NPG;                 // 64 graphs
    int NC  = Bn * 4;                  // 256 chunks

    // workspace carve-up
    float* t1   = (float*)d_ws;                        // N*8        4.1 MB
    float* u    = t1 + (size_t)N * HD;                 // N*8        4.1 MB
    int*   gcol = (int*)(u + (size_t)N * HD);          // E          8.2 MB
    int*   rpc  = gcol + (size_t)E;                    // NC*(NPG+1) 2.0 MB

    k_feat  <<<N / 64, 256, 0, stream>>>(x, W1a, t1, N);
    k_sort  <<<NC, 1024, 0, stream>>>(ei, gcol, rpc, E);
    k_l1    <<<Bn, 1024, 0, stream>>>(t1, rpc, gcol, u, b1a, W1b, b1b, W2a);
    k_l2fin <<<Bn, 1024, 0, stream>>>(u, rpc, gcol, b2a, W2b, b2b, Wf1, bf1,
                                      Wf2, bf2, (float*)d_out);
}

// Round 10
// 163.645 us; speedup vs baseline: 1.2889x; 1.2889x over previous
//
#include <hip/hip_runtime.h>
#include <math.h>

#define NF 128
#define HD 8
#define NPG 2000          // nodes per graph
#define EPB 8000          // edges per sort chunk (4 chunks per graph)
#define NPB 500           // nodes per layer block (4 blocks/graph)
#define SLOPE 0.01f

__device__ __forceinline__ float lrelu(float v) {
    return v > 0.0f ? v : SLOPE * v;
}

// ---------------------------------------------------------------------------
// K1: t1 = x @ W1a  (N x 128)@(128 x 8), coalesced via LDS staging.
// ---------------------------------------------------------------------------
__global__ __launch_bounds__(256) void k_feat(const float* __restrict__ x,
                                              const float* __restrict__ W1a,
                                              float* __restrict__ t1, int N) {
    __shared__ float tile[64 * 132];   // 33 KiB
    __shared__ float wl[NF * HD];      // 4 KiB

    const int t = threadIdx.x;
    const size_t base = (size_t)blockIdx.x * 64;

    ((float4*)wl)[t] = ((const float4*)W1a)[t];

    const float4* xg = (const float4*)(x + base * NF);
#pragma unroll
    for (int i = 0; i < 8; ++i) {
        int f4 = t + i * 256;
        float4 v = xg[f4];
        int flat = f4 * 4;
        int n = flat >> 7;
        int k = flat & 127;
        *(float4*)(tile + n * 132 + k) = v;
    }
    __syncthreads();

    const int n = t >> 2;
    const int c0 = (t & 3) * 2;
    float acc0 = 0.0f, acc1 = 0.0f;
    const float* row = tile + n * 132;
#pragma unroll
    for (int k4 = 0; k4 < 32; ++k4) {
        float4 r = *(const float4*)(row + k4 * 4);
        int kb = k4 * 4 * HD;
        acc0 += r.x * wl[kb + c0];          acc1 += r.x * wl[kb + c0 + 1];
        acc0 += r.y * wl[kb + HD + c0];     acc1 += r.y * wl[kb + HD + c0 + 1];
        acc0 += r.z * wl[kb + 2*HD + c0];   acc1 += r.z * wl[kb + 2*HD + c0 + 1];
        acc0 += r.w * wl[kb + 3*HD + c0];   acc1 += r.w * wl[kb + 3*HD + c0 + 1];
    }
    *(float2*)(t1 + (base + n) * HD + c0) = make_float2(acc0, acc1);
}

// ---------------------------------------------------------------------------
// K2: per-chunk counting sort, fully in LDS. 256 blocks (4 per graph).
// ---------------------------------------------------------------------------
__global__ __launch_bounds__(1024) void k_sort(const int* __restrict__ ei,
                                               int* __restrict__ gcol,
                                               int* __restrict__ rpc,
                                               int E) {
    __shared__ int cnt[NPG];      // counts -> cursors (8 KB)
    __shared__ int srt[EPB];      // sorted srcs (32 KB)
    __shared__ int wtot[16], wpre[16];

    const int b = blockIdx.x;     // chunk id
    const int g = b >> 2;
    const int tid = threadIdx.x;
    const int lane = tid & 63;
    const int wv = tid >> 6;
    const int nodeBase = g * NPG;
    const int e0 = b * EPB;

    for (int i = tid; i < NPG; i += 1024) cnt[i] = 0;
    __syncthreads();

    for (int e = e0 + tid; e < e0 + EPB; e += 1024) {
        int dl = ei[E + e] - nodeBase;
        atomicAdd(&cnt[dl], 1);               // native ds_add_u32
    }
    __syncthreads();

    int c0 = 0, c1 = 0;
    if (tid < 1000) { c0 = cnt[2 * tid]; c1 = cnt[2 * tid + 1]; }
    int s = c0 + c1;
    int isc = s;
#pragma unroll
    for (int d = 1; d < 64; d <<= 1) {
        int o = __shfl_up(isc, d);
        if (lane >= d) isc += o;
    }
    if (lane == 63) wtot[wv] = isc;
    __syncthreads();
    if (wv == 0) {
        int v = (lane < 16) ? wtot[lane] : 0;
        int iv = v;
#pragma unroll
        for (int d = 1; d < 16; d <<= 1) {
            int o = __shfl_up(iv, d);
            if (lane >= d) iv += o;
        }
        if (lane < 16) wpre[lane] = iv - v;
    }
    __syncthreads();
    int excl = isc - s + wpre[wv];

    int* rpb = rpc + (size_t)b * (NPG + 1);
    if (tid < 1000) {
        cnt[2 * tid]     = excl;
        cnt[2 * tid + 1] = excl + c0;
        rpb[2 * tid]     = excl;
        rpb[2 * tid + 1] = excl + c0;
    }
    if (tid == 0) rpb[NPG] = EPB;
    __syncthreads();

    for (int e = e0 + tid; e < e0 + EPB; e += 1024) {
        int src = ei[e] - nodeBase;               // LOCAL src
        int dl = ei[E + e] - nodeBase;
        int pos = atomicAdd(&cnt[dl], 1);         // ds_add_rtn_u32
        srt[pos] = src;
    }
    __syncthreads();

    int4* dst4 = (int4*)(gcol + (size_t)b * EPB);
    const int4* s4 = (const int4*)srt;
    for (int i = tid; i < EPB / 4; i += 1024) dst4[i] = s4[i];
}

// ---------------------------------------------------------------------------
// K3: layer 1. 4 blocks/graph x 512 thr (256 blocks -> full chip). Stage the
// graph's full t1 slice into LDS as SPLIT tables lo4[n]/hi4[n] (bank group =
// n%8, uniform — interleaved rows used only 4 of 8 groups), then 1 node per
// thread: gather from LDS, MLP1, u = h@W2a -> global.
// ---------------------------------------------------------------------------
__global__ __launch_bounds__(512) void k_l1(
    const float* __restrict__ t1, const int* __restrict__ rpc,
    const int* __restrict__ gcol, float* __restrict__ u,
    const float* __restrict__ b1a, const float* __restrict__ W1b,
    const float* __restrict__ b1b, const float* __restrict__ W2a)
{
    __shared__ float tbl[NPG * HD];   // 62.5 KiB: lo4[2000] then hi4[2000]
    __shared__ float wts[144];        // b1a[8] W1b[64] b1b[8] W2a[64]

    const int b = blockIdx.x;
    const int g = b >> 2;
    const int q = b & 3;
    const int tid = threadIdx.x;

    if (tid < 144) {
        float v;
        if (tid < 8)       v = b1a[tid];
        else if (tid < 72) v = W1b[tid - 8];
        else if (tid < 80) v = b1b[tid - 72];
        else               v = W2a[tid - 80];
        wts[tid] = v;
    }

    // stage slice: 4000 float4, split into lo/hi tables
    const float4* src4 = (const float4*)(t1 + (size_t)g * NPG * HD);
    float4* lo4 = (float4*)tbl;
    float4* hi4 = lo4 + NPG;
#pragma unroll
    for (int i = 0; i < 8; ++i) {
        int idx = tid + i * 512;
        if (idx < 2 * NPG) {
            float4 v = src4[idx];
            int n = idx >> 1;
            if (idx & 1) hi4[n] = v; else lo4[n] = v;
        }
    }
    __syncthreads();

    if (tid < NPB) {
        const int nl = q * NPB + tid;
        float a0 = 0, a1 = 0, a2 = 0, a3 = 0, a4 = 0, a5 = 0, a6 = 0, a7 = 0;
#pragma unroll
        for (int p = 0; p < 4; ++p) {
            const int* rpb  = rpc + (size_t)((g << 2) + p) * (NPG + 1);
            const int* colp = gcol + (size_t)((g << 2) + p) * EPB;
            int rs = rpb[nl], re = rpb[nl + 1];
            for (int e = rs; e < re; ++e) {
                int sl = colp[e];
                float4 pa = lo4[sl];
                float4 pb = hi4[sl];
                a0 += pa.x; a1 += pa.y; a2 += pa.z; a3 += pa.w;
                a4 += pb.x; a5 += pb.y; a6 += pb.z; a7 += pb.w;
            }
        }
        float4 tA = lo4[nl], tB = hi4[nl];     // self feature
        float z[HD];
        z[0] = lrelu(tA.x + a0 + wts[0]); z[1] = lrelu(tA.y + a1 + wts[1]);
        z[2] = lrelu(tA.z + a2 + wts[2]); z[3] = lrelu(tA.w + a3 + wts[3]);
        z[4] = lrelu(tB.x + a4 + wts[4]); z[5] = lrelu(tB.y + a5 + wts[5]);
        z[6] = lrelu(tB.z + a6 + wts[6]); z[7] = lrelu(tB.w + a7 + wts[7]);

        float h[HD];
#pragma unroll
        for (int j = 0; j < HD; ++j) {
            float acc = wts[72 + j];
#pragma unroll
            for (int c = 0; c < HD; ++c) acc += z[c] * wts[8 + c * HD + j];
            h[j] = lrelu(acc);
        }
        float uu[HD];
#pragma unroll
        for (int j = 0; j < HD; ++j) {
            float acc = 0.0f;
#pragma unroll
            for (int c = 0; c < HD; ++c) acc += h[c] * wts[80 + c * HD + j];
            uu[j] = acc;
        }
        float* ur = u + ((size_t)g * NPG + nl) * HD;
        *(float4*)ur       = make_float4(uu[0], uu[1], uu[2], uu[3]);
        *(float4*)(ur + 4) = make_float4(uu[4], uu[5], uu[6], uu[7]);
    }
}

// ---------------------------------------------------------------------------
// K4: layer 2. Same structure over u; MLP2 + FC1 + FC2 partials; plain-store
// per-block partial (no device-scope sync — R6 lesson). k_fin finalizes.
// ---------------------------------------------------------------------------
__global__ __launch_bounds__(512) void k_l2(
    const float* __restrict__ u, const int* __restrict__ rpc,
    const int* __restrict__ gcol,
    const float* __restrict__ b2a, const float* __restrict__ W2b,
    const float* __restrict__ b2b, const float* __restrict__ Wf1,
    const float* __restrict__ bf1, const float* __restrict__ Wf2,
    float* __restrict__ bparts)
{
    __shared__ float tbl[NPG * HD];   // 62.5 KiB split tables
    __shared__ float wts[89];         // b2a[8] W2b[64] b2b[8] Wf1[8] bf1[1]
    __shared__ float red[16];

    const int b = blockIdx.x;
    const int g = b >> 2;
    const int q = b & 3;
    const int tid = threadIdx.x;
    const int lane = tid & 63;
    const int wv = tid >> 6;

    if (tid < 89) {
        float v;
        if (tid < 8)       v = b2a[tid];
        else if (tid < 72) v = W2b[tid - 8];
        else if (tid < 80) v = b2b[tid - 72];
        else if (tid < 88) v = Wf1[tid - 80];
        else               v = bf1[0];
        wts[tid] = v;
    }

    const float4* src4 = (const float4*)(u + (size_t)g * NPG * HD);
    float4* lo4 = (float4*)tbl;
    float4* hi4 = lo4 + NPG;
#pragma unroll
    for (int i = 0; i < 8; ++i) {
        int idx = tid + i * 512;
        if (idx < 2 * NPG) {
            float4 v = src4[idx];
            int n = idx >> 1;
            if (idx & 1) hi4[n] = v; else lo4[n] = v;
        }
    }
    __syncthreads();

    float acc0 = 0.0f, acc1 = 0.0f;
    if (tid < NPB) {
        const int nl = q * NPB + tid;
        float a0 = 0, a1 = 0, a2 = 0, a3 = 0, a4 = 0, a5 = 0, a6 = 0, a7 = 0;
#pragma unroll
        for (int p = 0; p < 4; ++p) {
            const int* rpb  = rpc + (size_t)((g << 2) + p) * (NPG + 1);
            const int* colp = gcol + (size_t)((g << 2) + p) * EPB;
            int rs = rpb[nl], re = rpb[nl + 1];
            for (int e = rs; e < re; ++e) {
                int sl = colp[e];
                float4 pa = lo4[sl];
                float4 pb = hi4[sl];
                a0 += pa.x; a1 += pa.y; a2 += pa.z; a3 += pa.w;
                a4 += pb.x; a5 += pb.y; a6 += pb.z; a7 += pb.w;
            }
        }
        float4 uA = lo4[nl], uB = hi4[nl];
        float z[HD];
        z[0] = lrelu(uA.x + a0 + wts[0]); z[1] = lrelu(uA.y + a1 + wts[1]);
        z[2] = lrelu(uA.z + a2 + wts[2]); z[3] = lrelu(uA.w + a3 + wts[3]);
        z[4] = lrelu(uB.x + a4 + wts[4]); z[5] = lrelu(uB.y + a5 + wts[5]);
        z[6] = lrelu(uB.z + a6 + wts[6]); z[7] = lrelu(uB.w + a7 + wts[7]);

        float sv = wts[88];
#pragma unroll
        for (int j = 0; j < HD; ++j) {
            float acc = wts[72 + j];
#pragma unroll
            for (int c = 0; c < HD; ++c) acc += z[c] * wts[8 + c * HD + j];
            sv += lrelu(acc) * wts[80 + j];
        }
        float pf = lrelu(sv);
        float2 wf = *(const float2*)(Wf2 + (size_t)nl * 2);
        acc0 = pf * wf.x;
        acc1 = pf * wf.y;
    }

#pragma unroll
    for (int off = 32; off > 0; off >>= 1) {
        acc0 += __shfl_down(acc0, off);
        acc1 += __shfl_down(acc1, off);
    }
    if (lane == 0) { red[wv * 2] = acc0; red[wv * 2 + 1] = acc1; }
    __syncthreads();

    if (tid == 0) {
        float y0 = 0.f, y1 = 0.f;
#pragma unroll
        for (int w = 0; w < 8; ++w) { y0 += red[w * 2]; y1 += red[w * 2 + 1]; }
        *(float2*)(bparts + (size_t)b * 2) = make_float2(y0, y1);
    }
}

// ---------------------------------------------------------------------------
// K5: finalize — one thread per graph sums 4 block partials, log_softmax.
// ---------------------------------------------------------------------------
__global__ __launch_bounds__(64) void k_fin(const float* __restrict__ bparts,
                                            const float* __restrict__ bf2,
                                            float* __restrict__ out, int Bn) {
    int g = threadIdx.x;
    if (g >= Bn) return;
    float y0 = bf2[0], y1 = bf2[1];
#pragma unroll
    for (int b = 0; b < 4; ++b) {
        float2 v = *(const float2*)(bparts + (size_t)(g * 4 + b) * 2);
        y0 += v.x; y1 += v.y;
    }
    float m = fmaxf(y0, y1);
    float lse = m + logf(expf(y0 - m) + expf(y1 - m));
    out[g * 2 + 0] = y0 - lse;
    out[g * 2 + 1] = y1 - lse;
}

// ---------------------------------------------------------------------------
extern "C" void kernel_launch(void* const* d_in, const int* in_sizes, int n_in,
                              void* d_out, int out_size, void* d_ws, size_t ws_size,
                              hipStream_t stream) {
    const float* x   = (const float*)d_in[0];
    const int*   ei  = (const int*)  d_in[1];
    const float* W1a = (const float*)d_in[3];
    const float* b1a = (const float*)d_in[4];
    const float* W1b = (const float*)d_in[5];
    const float* b1b = (const float*)d_in[6];
    const float* W2a = (const float*)d_in[7];
    const float* b2a = (const float*)d_in[8];
    const float* W2b = (const float*)d_in[9];
    const float* b2b = (const float*)d_in[10];
    const float* Wf1 = (const float*)d_in[11];
    const float* bf1 = (const float*)d_in[12];
    const float* Wf2 = (const float*)d_in[13];
    const float* bf2 = (const float*)d_in[14];

    int N   = in_sizes[0] / NF;        // 128000
    int E   = in_sizes[1] / 2;         // 2048000
    int Bn  = N / NPG;                 // 64 graphs
    int NC  = Bn * 4;                  // 256 chunks

    // workspace carve-up
    float* t1     = (float*)d_ws;                        // N*8        4.1 MB
    float* u      = t1 + (size_t)N * HD;                 // N*8        4.1 MB
    int*   gcol   = (int*)(u + (size_t)N * HD);          // E          8.2 MB
    int*   rpc    = gcol + (size_t)E;                    // NC*(NPG+1) 2.0 MB
    float* bparts = (float*)(rpc + (size_t)NC * (NPG + 1) + 16);  // 256*2

    k_feat <<<N / 64, 256, 0, stream>>>(x, W1a, t1, N);
    k_sort <<<NC, 1024, 0, stream>>>(ei, gcol, rpc, E);
    k_l1   <<<NC, 512, 0, stream>>>(t1, rpc, gcol, u, b1a, W1b, b1b, W2a);
    k_l2   <<<NC, 512, 0, stream>>>(u, rpc, gcol, b2a, W2b, b2b, Wf1, bf1,
                                    Wf2, bparts);
    k_fin  <<<1, 64, 0, stream>>>(bparts, bf2, (float*)d_out, Bn);
}